// Round 5
// baseline (330.608 us; speedup 1.0000x reference)
//
#include <hip/hip_runtime.h>
#include <hip/hip_fp16.h>
#include <math.h>

// SpinSphericalBlock: separable spin-weighted SHT -> channel mix -> inverse SHT
// -> complex BN (spin0 mean, via Parseval on G) -> magnitude-ReLU gating.
//
// Constants: B=8, RES=64, RES_OUT=32, L=15, SPINS_IN=(0,1), SPINS_OUT=(0,1,2),
// C_IN=64, C_OUT=128, NM=31. Output: out_size=3,145,728 float32 = Re(y),
// (b,t,p,s,d) row-major (established R0-R4).
//
// R21 post-mortem of R19/R20: R19 cooperative launch likely failed at graph
// capture (unchecked return -> kernel never ran). R20 manual barrier had
// exact-capacity grid (512 blk @ 2/CU) -> any occupancy shortfall deadlocks;
// 2M x s_sleep(8) bailout ~0.4s/barrier -> minutes over graph replays ->
// container timeout. Fix (un-deadlockable by construction):
//   * grid 256 x 256: 1 block/CU guaranteed resident (4 waves/CU, ~160 VGPR,
//     20KB LDS). Each phase loops 2 logical blocks.
//   * barrier counter zeroed via hipMemsetAsync in kernel_launch (capture-
//     legal) -> fixed targets 256/512/768/1024, immune to ws poisoning.
//   * bailout 200k x s_sleep(2) ~10ms -> bounded worst case, fails loudly
//     (absmax) instead of hanging.
// Phase math is the verbatim proven R18 5-kernel pipeline.
//
//   P1: W-pack (float4) + Wigner tables (fp64) + stats zero + phi-DFT -> F
//   P2: theta-in   coeffs[b,k,iu] = sum_t A_in[i,k,t] F[b,t,m(k),iu]
//   P3: mix        oc[b,k,sd]     = sum_iu coeffs * W[l(k),i,s,u,d]
//   P4: theta-out  G[bt,m,sd]     = sum_l A_out[s,k,t] oc[b,k,sd]  + stats
//   P5: y = BN(sum_m G e^{+im phi'_p}) -> gate -> Re(y) (radix-2)

#define PI_D 3.14159265358979323846

// ---------------- workspace layout (bytes) ----------------
#define OFF_A_IN    ((size_t)24320)     // 2*256*64 float    = 131072
#define OFF_A_OUT   ((size_t)155648)    // 3*256*32 float    = 98304
#define OFF_STATS   ((size_t)254208)    // 3*384 float       = 4608
#define OFF_BAR     ((size_t)259072)    // grid-barrier counter (64 B)
#define OFF_R1      ((size_t)260608)    // F fp16 (8.1MB) then oc fp16 (3.1MB)
#define OFF_R2      ((size_t)25426688)  // coeffs fp16 (1MB) then G fp16 (12.2MB)
#define OFF_W       ((size_t)67108864)  // packed weights float4 (6.3MB)

// ln(j!) for j=0..30
__constant__ double LF[31] = {
    0.0, 0.0, 0.6931471805599453, 1.791759469228055, 3.1780538303479458,
    4.787491742782046, 6.579251212010101, 8.525161361065415,
    10.604602902745251, 12.801827480081469, 15.104412573075516,
    17.502307845873887, 19.987214495661885, 22.552163853123425,
    25.19122118273868, 27.89927138384089, 30.671860106080672,
    33.50507345013689, 36.39544520803305, 39.339884187199495,
    42.335616460753485, 45.38013889847691, 48.47118135183523,
    51.60667556776438, 54.78472939811232, 58.00360522298052,
    61.261701761002, 64.55753862700634, 67.88974313718154,
    71.25703896716801, 74.65823634883016};

__device__ inline int isqrt_k(int k) {
    int l = (int)sqrtf((float)k + 0.5f);
    while (l * l > k) --l;
    while ((l + 1) * (l + 1) <= k) ++l;
    return l;
}

// d^l_{m,n}(theta) via seed term (1 exp + 2 log) + exact ratio recurrence.
__device__ double wigner_d_rec(int l, int m, int n, double theta) {
    int an = n < 0 ? -n : n;
    int am = m < 0 ? -m : m;
    if (l < an || l < am) return 0.0;
    int kmin = max(0, n - m), kmax = min(l + n, l - m);
    if (kmax < kmin) return 0.0;
    double cb = cos(0.5 * theta), sb = sin(0.5 * theta);
    double pref = 0.5 * (LF[l + m] + LF[l - m] + LF[l + n] + LF[l - n]);
    double lterm = pref
        - (LF[l + n - kmin] + LF[kmin] + LF[m - n + kmin] + LF[l - m - kmin])
        + (double)(2 * l + n - m - 2 * kmin) * log(cb)
        + (double)(m - n + 2 * kmin) * log(sb);
    double term = exp(lterm);
    if ((m - n + kmin) & 1) term = -term;
    double r = (sb * sb) / (cb * cb);
    double acc = term;
    for (int k = kmin; k < kmax; ++k) {
        term *= -((double)((l + n - k) * (l - m - k)) * r)
                / ((double)((k + 1) * (m - n + k + 1)));
        acc += term;
    }
    return acc;
}

// Manual grid barrier. Counter is zeroed by host memset each launch, so
// targets are absolute (256*phase). Agent-scope fences handle cross-XCD
// visibility (L2 writeback on release, invalidate on acquire). Bounded
// bailout (~10ms) turns any residual pathology into a wrong-answer signal
// instead of a hang.
__device__ __forceinline__ void gbar(unsigned* bar, unsigned target) {
    __syncthreads();
    if (threadIdx.x == 0) {
        __threadfence();  // release: publish this block's stores
        __hip_atomic_fetch_add(bar, 1u, __ATOMIC_RELEASE,
                               __HIP_MEMORY_SCOPE_AGENT);
        unsigned tries = 0;
        while (__hip_atomic_load(bar, __ATOMIC_ACQUIRE,
                                 __HIP_MEMORY_SCOPE_AGENT) < target) {
            __builtin_amdgcn_s_sleep(2);
            if (++tries > 200000u) break;  // ~10 ms bound
        }
        __threadfence();  // acquire: drop stale lines
    }
    __syncthreads();
}

__global__ __launch_bounds__(256, 1) void k_mega(
    const float* __restrict__ xr, const float* __restrict__ xi,
    const float* __restrict__ kr, const float* __restrict__ ki,
    const float* __restrict__ gamma, const float* __restrict__ betar,
    const float* __restrict__ betai, const float* __restrict__ bias,
    float* __restrict__ out,
    float* __restrict__ A_in, float* __restrict__ A_out,
    float* __restrict__ stats,
    __half2* __restrict__ F, __half2* __restrict__ coeffs,
    __half2* __restrict__ oc, __half2* __restrict__ G,
    float4* __restrict__ W, unsigned* __restrict__ bar) {
    __shared__ union {
        struct { float A[16][64]; float2 red[2][16][64]; } p2;  // 20 KB
        struct { float2 cs[4][128]; } p3;                       // 4 KB
        struct { float Ao[3][16][32]; } p4;                     // 6 KB
    } sm;

    float* ssr = stats;
    float* ssi = stats + 384;
    float* ssq = stats + 768;

    int bid = blockIdx.x, tid = threadIdx.x;
    int gidx = bid * 256 + tid;

    // ================= P1: W-pack + tables + stats zero + phi-DFT =========
    {
        const float2* kr2 = (const float2*)kr;
        const float2* ki2 = (const float2*)ki;
#pragma unroll
        for (int j = 0; j < 6; ++j) {
            int e = gidx + j * 65536;    // 6*65536 = 393216 float4
            int dp = e & 63, r = e >> 6; // r = lis*64+u < 6144
            float2 a = kr2[(size_t)r * 64 + dp];
            float2 b = ki2[(size_t)r * 64 + dp];
            W[e] = make_float4(a.x, a.y, b.x, b.y);
        }
        if (gidx < 32768) {
            int idx = gidx;
            int t = idx & 63, k = (idx >> 6) & 255, i = idx >> 14;
            int l = isqrt_k(k);
            int m = k - l * l - l;
            double theta = ((double)t + 0.5) * PI_D / 64.0;
            double w = sin(theta) * (PI_D / 64.0) * (2.0 * PI_D / 64.0);
            double norm = sqrt((2.0 * l + 1.0) / (4.0 * PI_D));
            double d = wigner_d_rec(l, m, -i, theta);
            A_in[idx] = (float)(((m & 1) ? -1.0 : 1.0) * norm * w * d);
        } else if (gidx < 57344) {
            int idx = gidx - 32768;
            int t = idx & 31, k = (idx >> 5) & 255, s = idx >> 13;
            int l = isqrt_k(k);
            int m = k - l * l - l;
            double theta = ((double)t + 0.5) * PI_D / 32.0;
            double norm = sqrt((2.0 * l + 1.0) / (4.0 * PI_D));
            double d = wigner_d_rec(l, m, -s, theta);
            A_out[idx] = (float)(((m & 1) ? -1.0 : 1.0) * norm * d);
        } else if (gidx < 58496) {
            stats[gidx - 57344] = 0.f;
        }
    }
    // ---- phi-DFT: 2 bt per block, 16 m's per thread ----
    for (int rr = 0; rr < 2; ++rr) {
        int bt = bid + 256 * rr;
        int iu = tid & 127, mh2 = tid >> 7;  // 0..1, 16 m's each
        float2 acc[16], w[16], st[16];
#pragma unroll
        for (int j = 0; j < 16; ++j) {
            int m = mh2 * 16 + j - 15;
            float sy, sx;
            __sincosf(-(float)m * (float)(PI_D / 32.0), &sy, &sx);
            st[j] = make_float2(sx, sy);
            w[j] = make_float2(1.f, 0.f);
            acc[j] = make_float2(0.f, 0.f);
        }
        const float* xrb = xr + (size_t)bt * 8192 + iu;
        const float* xib = xi + (size_t)bt * 8192 + iu;
        for (int p = 0; p < 32; ++p) {
            float a  = xrb[(size_t)p * 128];
            float b  = xib[(size_t)p * 128];
            float a2 = xrb[(size_t)(p + 32) * 128];
            float b2 = xib[(size_t)(p + 32) * 128];
            float sar = a + a2, sai = b + b2;   // even m
            float dar = a - a2, dai = b - b2;   // odd m
#pragma unroll
            for (int j = 0; j < 16; ++j) {
                float ur = (j & 1) ? sar : dar;  // j odd -> m even
                float ui = (j & 1) ? sai : dai;
                acc[j].x += ur * w[j].x - ui * w[j].y;
                acc[j].y += ur * w[j].y + ui * w[j].x;
                float nx = w[j].x * st[j].x - w[j].y * st[j].y;
                w[j].y = w[j].x * st[j].y + w[j].y * st[j].x;
                w[j].x = nx;
            }
        }
        __half2* Fb = F + (size_t)bt * 31 * 128 + iu;
#pragma unroll
        for (int j = 0; j < 16; ++j) {
            int mi = mh2 * 16 + j;
            if (mi < 31) Fb[(size_t)mi * 128] = __float22half2_rn(acc[j]);
        }
    }
    gbar(bar, 256);

    // ================= P2: theta-in contraction (2 logical blocks) =========
    for (int rr = 0; rr < 2; ++rr) {
        int lb = bid + 256 * rr;
        if (lb < 496) {
            int mi = lb % 31;
            int q = lb / 31;
            int b = q >> 1, z = q & 1;  // z = i
            int m = mi - 15;
            int am = m < 0 ? -m : m;
            for (int idx = tid; idx < 1024; idx += 256) {
                int j = idx >> 6, t = idx & 63;
                float v = 0.f;
                if (j >= am) v = A_in[((size_t)z * 256 + (j * j + j + m)) * 64 + t];
                sm.p2.A[j][t] = v;
            }
            __syncthreads();
            int iu_l = tid & 63, th = tid >> 6;
            int iu = z * 64 + iu_l;
            float2 acc[16];
#pragma unroll
            for (int j = 0; j < 16; ++j) acc[j] = make_float2(0.f, 0.f);
            const __half2* Fb = F + ((size_t)b * 64 * 31 + mi) * 128 + iu;
            for (int tt = 0; tt < 16; ++tt) {
                int t = th * 16 + tt;
                float2 f = __half22float2(Fb[(size_t)t * 31 * 128]);
#pragma unroll
                for (int j = 0; j < 16; ++j) {
                    float a = sm.p2.A[j][t];
                    acc[j].x += a * f.x;
                    acc[j].y += a * f.y;
                }
            }
            if (th >= 2) {
#pragma unroll
                for (int j = 0; j < 16; ++j) sm.p2.red[th - 2][j][iu_l] = acc[j];
            }
            __syncthreads();
            if (th < 2) {
#pragma unroll
                for (int j = 0; j < 16; ++j) {
                    float2 r = sm.p2.red[th][j][iu_l];
                    acc[j].x += r.x;
                    acc[j].y += r.y;
                }
            }
            __syncthreads();
            if (th == 1) {
#pragma unroll
                for (int j = 0; j < 16; ++j) sm.p2.red[0][j][iu_l] = acc[j];
            }
            __syncthreads();
            if (th == 0) {
#pragma unroll
                for (int j = 0; j < 16; ++j) {
                    if (j >= am) {
                        float2 r = sm.p2.red[0][j][iu_l];
                        coeffs[((size_t)b * 256 + (j * j + j + m)) * 128 + iu] =
                            __float22half2_rn(
                                make_float2(acc[j].x + r.x, acc[j].y + r.y));
                    }
                }
            }
        }
        __syncthreads();  // protect LDS reuse across logical blocks
    }
    gbar(bar, 512);

    // ================= P3: channel mix (2 logical blocks) ==================
    for (int rr = 0; rr < 2; ++rr) {
        int lb = bid + 256 * rr;
        int y = lb >> 8;                  // b-group
        int bxk = lb & 255;
        int k = ((bxk & 7) << 5) + (bxk >> 3);  // XCD-chunked k
        int b0 = y * 4;
        for (int idx = tid; idx < 512; idx += 256) {
            int bb = idx >> 7, iuu = idx & 127;
            sm.p3.cs[bb][iuu] =
                __half22float2(coeffs[((size_t)(b0 + bb) * 256 + k) * 128 + iuu]);
        }
        __syncthreads();
        if (tid < 192) {
            int s = tid >> 6, dp = tid & 63;
            int l = isqrt_k(k);
            float2 acc[4][2];
#pragma unroll
            for (int bb = 0; bb < 4; ++bb) {
                acc[bb][0] = make_float2(0.f, 0.f);
                acc[bb][1] = make_float2(0.f, 0.f);
            }
            const float4* W0 = W + (size_t)(6 * l + s) * 4096 + dp;  // i=0
            const float4* W1 = W0 + (size_t)3 * 4096;                // i=1
            float4 cur[4];
#pragma unroll
            for (int j = 0; j < 4; ++j) cur[j] = W0[(size_t)j * 64];
            for (int g = 0; g < 32; ++g) {
                float4 nxt[4];
                if (g < 31) {
                    int iu0 = (g + 1) * 4;
                    const float4* P = (iu0 < 64) ? (W0 + (size_t)iu0 * 64)
                                                 : (W1 + (size_t)(iu0 - 64) * 64);
#pragma unroll
                    for (int j = 0; j < 4; ++j) nxt[j] = P[(size_t)j * 64];
                }
#pragma unroll
                for (int j = 0; j < 4; ++j) {
                    int iu = g * 4 + j;
                    float2 wr = make_float2(cur[j].x, cur[j].y);
                    float2 wi = make_float2(cur[j].z, cur[j].w);
#pragma unroll
                    for (int bb = 0; bb < 4; ++bb) {
                        float2 cv = sm.p3.cs[bb][iu];
                        acc[bb][0].x += cv.x * wr.x - cv.y * wi.x;
                        acc[bb][0].y += cv.x * wi.x + cv.y * wr.x;
                        acc[bb][1].x += cv.x * wr.y - cv.y * wi.y;
                        acc[bb][1].y += cv.x * wi.y + cv.y * wr.y;
                    }
                }
                if (g < 31) {
#pragma unroll
                    for (int j = 0; j < 4; ++j) cur[j] = nxt[j];
                }
            }
#pragma unroll
            for (int bb = 0; bb < 4; ++bb) {
                size_t o = ((size_t)(b0 + bb) * 256 + k) * 384 + s * 128 + 2 * dp;
                oc[o]     = __float22half2_rn(acc[bb][0]);
                oc[o + 1] = __float22half2_rn(acc[bb][1]);
            }
        }
        __syncthreads();  // protect cs reuse across logical blocks
    }
    gbar(bar, 768);

    // ================= P4: theta expansion + G store + stats ===============
    for (int rr = 0; rr < 2; ++rr) {
        int lb = bid + 256 * rr;
        if (lb < 496) {
            int mi = lb % 31;
            int q = lb / 31;
            int b = q >> 1, z = q & 1;
            int m = mi - 15;
            int am = m < 0 ? -m : m;
            for (int idx = tid; idx < 1536; idx += 256) {
                int s = idx >> 9, j = (idx >> 5) & 15, t = idx & 31;
                float v = 0.f;
                if (j >= am) v = A_out[((size_t)s * 256 + (j * j + j + m)) * 32 + t];
                sm.p4.Ao[s][j][t] = v;
            }
            __syncthreads();
            if (tid < 192) {
                int sd = z * 192 + tid;
                int s = sd >> 7;
                float2 c[16];
#pragma unroll
                for (int j = 0; j < 16; ++j) {
                    c[j] = make_float2(0.f, 0.f);
                    if (j >= am)
                        c[j] = __half22float2(
                            oc[((size_t)b * 256 + (j * j + j + m)) * 384 + sd]);
                }
                float sq = 0.f, sr = 0.f, si = 0.f;
                for (int t = 0; t < 32; ++t) {
                    float fr = 0.f, fi = 0.f;
#pragma unroll
                    for (int j = 0; j < 16; ++j) {
                        float a = sm.p4.Ao[s][j][t];
                        fr += a * c[j].x;
                        fi += a * c[j].y;
                    }
                    G[(((size_t)b * 32 + t) * 31 + mi) * 384 + sd] =
                        __float22half2_rn(make_float2(fr, fi));
                    sq += fr * fr + fi * fi;
                    if (mi == 15) { sr += fr; si += fi; }
                }
                atomicAdd(&ssq[sd], sq);
                if (mi == 15) {
                    atomicAdd(&ssr[sd], sr);
                    atomicAdd(&ssi[sd], si);
                }
            }
        }
        __syncthreads();  // protect Ao reuse across logical blocks
    }
    gbar(bar, 1024);

    // ================= P5: phi synthesis + BN + gate (no LDS) ==============
    for (int rr = 0; rr < 2; ++rr) {
        int lb = bid + 256 * rr;
        int bt = lb >> 1, half = lb & 1;
        if (tid < 192) {
            int sd = half * 192 + tid;
            int s = sd >> 7;
            float2 g[31], st[31];
#pragma unroll
            for (int mi = 0; mi < 31; ++mi) {
                g[mi] = __half22float2(G[((size_t)bt * 31 + mi) * 384 + sd]);
                float sy, sx;
                __sincosf((float)(mi - 15) * (float)(PI_D / 16.0), &sy, &sx);
                st[mi] = make_float2(sx, sy);
            }
            const float invN = 1.0f / 256.0f;
            float mur = 0.f, mui = 0.f;
            if (s == 0) { mur = ssr[sd] * invN; mui = ssi[sd] * invN; }
            float var = ssq[sd] * invN - (mur * mur + mui * mui);
            float scale = gamma[sd] / sqrtf(var + 1e-5f);
            float br = (s == 0) ? betar[sd] : 0.f;
            float bi = (s == 0) ? betai[sd] : 0.f;
            float bb = bias[sd];
            float* ob = out + (size_t)bt * 32 * 384 + sd;
            for (int p = 0; p < 16; ++p) {
                float fr = 0.f, fi = 0.f, fr2 = 0.f, fi2 = 0.f;
#pragma unroll
                for (int mi = 0; mi < 31; ++mi) {
                    fr += g[mi].x;
                    fi += g[mi].y;
                    if (mi & 1) { fr2 += g[mi].x; fi2 += g[mi].y; }  // m even
                    else        { fr2 -= g[mi].x; fi2 -= g[mi].y; }  // m odd
                }
                {
                    float yr = (fr - mur) * scale + br;
                    float yi = (fi - mui) * scale + bi;
                    float mag = sqrtf(yr * yr + yi * yi);
                    float f = fmaxf(mag + bb, 0.f) / (mag + 1e-6f);
                    ob[(size_t)p * 384] = yr * f;
                }
                {
                    float yr = (fr2 - mur) * scale + br;
                    float yi = (fi2 - mui) * scale + bi;
                    float mag = sqrtf(yr * yr + yi * yi);
                    float f = fmaxf(mag + bb, 0.f) / (mag + 1e-6f);
                    ob[(size_t)(p + 16) * 384] = yr * f;
                }
#pragma unroll
                for (int mi = 0; mi < 31; ++mi) {
                    float nx = g[mi].x * st[mi].x - g[mi].y * st[mi].y;
                    g[mi].y = g[mi].x * st[mi].y + g[mi].y * st[mi].x;
                    g[mi].x = nx;
                }
            }
        }
    }
}

extern "C" void kernel_launch(void* const* d_in, const int* in_sizes, int n_in,
                              void* d_out, int out_size, void* d_ws, size_t ws_size,
                              hipStream_t stream) {
    const float* xr    = (const float*)d_in[0];
    const float* xi    = (const float*)d_in[1];
    const float* kr    = (const float*)d_in[2];
    const float* ki    = (const float*)d_in[3];
    const float* gamma = (const float*)d_in[4];
    const float* betar = (const float*)d_in[5];
    const float* betai = (const float*)d_in[6];
    const float* bias  = (const float*)d_in[7];
    float* out = (float*)d_out;

    char* ws = (char*)d_ws;
    float*   A_in   = (float*)(ws + OFF_A_IN);
    float*   A_out  = (float*)(ws + OFF_A_OUT);
    float*   stats  = (float*)(ws + OFF_STATS);
    unsigned* bar   = (unsigned*)(ws + OFF_BAR);
    __half2* F      = (__half2*)(ws + OFF_R1);  // aliased: oc after P2
    __half2* oc     = (__half2*)(ws + OFF_R1);
    __half2* coeffs = (__half2*)(ws + OFF_R2);  // aliased: G after P3
    __half2* G      = (__half2*)(ws + OFF_R2);
    float4*  W      = (float4*)(ws + OFF_W);

    hipMemsetAsync(ws + OFF_BAR, 0, 64, stream);  // zero barrier counter
    k_mega<<<256, 256, 0, stream>>>(xr, xi, kr, ki, gamma, betar, betai, bias,
                                    out, A_in, A_out, stats, F, coeffs, oc, G,
                                    W, bar);
}